// Round 8
// baseline (468.926 us; speedup 1.0000x reference)
//
#include <hip/hip_runtime.h>

#define D_IN   4096
#define D_OUT  4096
#define N_TOK  8192
#define RANK   16
#define NEXP   8
#define ER     128          // NEXP*RANK — lora inner width
#define KCAT   4224         // D_IN + ER — concatenated K
#define SCALING 2.0f        // 32/16

typedef __attribute__((ext_vector_type(8))) short short8;     // 8 bf16 (4 VGPR)
typedef __attribute__((ext_vector_type(4))) float f32x4;
typedef __attribute__((ext_vector_type(4))) unsigned short us4;
typedef unsigned int uint;

__device__ __forceinline__ unsigned short f2bf(float f) {
  unsigned u = __float_as_uint(f);
  u += 0x7FFFu + ((u >> 16) & 1u);     // RNE
  return (unsigned short)(u >> 16);
}

__device__ __forceinline__ void gload_lds16(const void* g, void* l) {
  __builtin_amdgcn_global_load_lds(
      (const __attribute__((address_space(1))) unsigned int*)g,
      (__attribute__((address_space(3))) unsigned int*)l, 16, 0, 0);
}

// ---------------- kernel 1: fused prep + router -------------------------
__global__ __launch_bounds__(256) void fused_prep_router_kernel(
    const float* __restrict__ X, const float* __restrict__ Wr,
    const float* __restrict__ W, const float* __restrict__ A,
    const float* __restrict__ B,
    unsigned short* __restrict__ Xcat, float* __restrict__ Comb,
    unsigned short* __restrict__ Wcat, unsigned short* __restrict__ Ab) {
  if (blockIdx.x < 512) {
    int wave = threadIdx.x >> 6, lane = threadIdx.x & 63;
    int tok0 = blockIdx.x * 16 + wave * 4;
    float acc[4][8];
#pragma unroll
    for (int t = 0; t < 4; ++t)
#pragma unroll
      for (int e = 0; e < 8; ++e) acc[t][e] = 0.f;
    const float4* X4 = (const float4*)X;
    const float4* W4 = (const float4*)Wr;
#pragma unroll 1
    for (int it = 0; it < 16; ++it) {
      int kq = it * 64 + lane;
      float4 w[8];
#pragma unroll
      for (int e = 0; e < 8; ++e) w[e] = W4[e * 1024 + kq];
#pragma unroll
      for (int t = 0; t < 4; ++t) {
        float4 xv = X4[(size_t)(tok0 + t) * 1024 + kq];
        us4 xb = { f2bf(xv.x), f2bf(xv.y), f2bf(xv.z), f2bf(xv.w) };
        ((us4*)(Xcat + (size_t)(tok0 + t) * KCAT))[kq] = xb;
#pragma unroll
        for (int e = 0; e < 8; ++e)
          acc[t][e] = fmaf(xv.x, w[e].x, fmaf(xv.y, w[e].y,
                       fmaf(xv.z, w[e].z, fmaf(xv.w, w[e].w, acc[t][e]))));
      }
    }
#pragma unroll
    for (int t = 0; t < 4; ++t)
#pragma unroll
      for (int e = 0; e < 8; ++e) {
        float v = acc[t][e];
        for (int off = 32; off; off >>= 1) v += __shfl_xor(v, off, 64);
        acc[t][e] = v;
      }
#pragma unroll
    for (int t = 0; t < 4; ++t) {
      float m1 = acc[t][0]; int i1 = 0;
#pragma unroll
      for (int e = 1; e < 8; ++e) if (acc[t][e] > m1) { m1 = acc[t][e]; i1 = e; }
      float m2 = -1e30f; int i2 = 0;
#pragma unroll
      for (int e = 0; e < 8; ++e)
        if (e != i1 && acc[t][e] > m2) { m2 = acc[t][e]; i2 = e; }
      float w1 = 1.f / (1.f + expf(m2 - m1));
      if (lane < 8) {
        float v = (lane == i1) ? w1 : (lane == i2) ? (1.f - w1) : 0.f;
        Comb[(size_t)(tok0 + t) * 8 + lane] = v * SCALING;
      }
    }
  } else {
    const int NW4 = (D_OUT * D_IN) / 4;
    const int NA4 = (ER * D_IN) / 4;
    const int NB4 = (D_OUT * ER) / 4;
    const int total = NW4 + NA4 + NB4;
    const int stride = 2048 * 256;
    for (int i = (blockIdx.x - 512) * blockDim.x + threadIdx.x; i < total;
         i += stride) {
      if (i < NW4) {
        float4 v = ((const float4*)W)[i];
        us4 o = { f2bf(v.x), f2bf(v.y), f2bf(v.z), f2bf(v.w) };
        int row = i >> 10, kq = i & 1023;
        ((us4*)(Wcat + (size_t)row * KCAT))[kq] = o;
      } else if (i < NW4 + NA4) {
        int j = i - NW4;
        float4 v = ((const float4*)A)[j];
        us4 o = { f2bf(v.x), f2bf(v.y), f2bf(v.z), f2bf(v.w) };
        ((us4*)Ab)[j] = o;
      } else {
        int j = i - NW4 - NA4;
        int o = j >> 5; int rem = j & 31; int e = rem >> 2; int rq = rem & 3;
        float4 v = *(const float4*)(B + (size_t)e * D_OUT * RANK + o * RANK + rq * 4);
        us4 ob = { f2bf(v.x), f2bf(v.y), f2bf(v.z), f2bf(v.w) };
        *(us4*)(Wcat + (size_t)o * KCAT + D_IN + e * 16 + rq * 4) = ob;
      }
    }
  }
}

// ---------------- kernel 3: h = x_bf @ A_all^T, weighted -> Xcat[:,4096+] ---
#define HSTG(S) { const uint hbase = (S) * 40960u; \
  _Pragma("unroll") for (int c = 0; c < 2; ++c) { gload_lds16(pa[c], ldsc + hbase + da[c]); pa[c] += 128; } \
  _Pragma("unroll") for (int c = 0; c < 8; ++c) { gload_lds16(pb[c], ldsc + hbase + db[c]); pb[c] += 128; } }

#define HTILE(S, S2, DOSTG, VM) { const uint hb = (S) * 40960u; \
  short8 af[4]; short8 bfr[4][4]; \
  _Pragma("unroll") for (int kk = 0; kk < 4; ++kk) af[kk] = *(const short8*)(ldsc + hb + oA[kk]); \
  _Pragma("unroll") for (int n = 0; n < 4; ++n) \
    _Pragma("unroll") for (int kk = 0; kk < 4; ++kk) bfr[n][kk] = *(const short8*)(ldsc + hb + oB[n][kk]); \
  if (DOSTG) HSTG(S2); \
  __builtin_amdgcn_sched_barrier(0); __builtin_amdgcn_s_barrier(); __builtin_amdgcn_sched_barrier(0); \
  __builtin_amdgcn_s_setprio(1); \
  _Pragma("unroll") for (int kk = 0; kk < 4; ++kk) \
    _Pragma("unroll") for (int n = 0; n < 4; ++n) \
      acc[n] = __builtin_amdgcn_mfma_f32_16x16x32_bf16(af[kk], bfr[n][kk], acc[n], 0, 0, 0); \
  __builtin_amdgcn_s_setprio(0); \
  __builtin_amdgcn_sched_barrier(0); \
  asm volatile("s_waitcnt vmcnt(" #VM ")" ::: ); \
  __builtin_amdgcn_s_barrier(); __builtin_amdgcn_sched_barrier(0); }

__global__ __launch_bounds__(256, 1) void h_gemm_kernel(
    unsigned short* Xcat, const unsigned short* __restrict__ Ab,
    const float* __restrict__ Comb) {
  __shared__ unsigned short hlds[61440];     // 3 x 40960 B
  char* ldsc = (char*)hlds;
  const int tid = threadIdx.x, wave = tid >> 6, lane = tid & 63;
  const int wm = wave >> 1, wn = wave & 1;
  const int row0 = blockIdx.x * 32;

  const unsigned short* pa[2]; uint da[2];
#pragma unroll
  for (int c = 0; c < 2; ++c) {
    int ch = c * 256 + tid, row = ch >> 4, s = ch & 15;
    pa[c] = Xcat + (size_t)(row0 + row) * KCAT + (s ^ ((row >> 1) & 7)) * 8;
    da[c] = (uint)ch * 16;
  }
  const unsigned short* pb[8]; uint db[8];
#pragma unroll
  for (int c = 0; c < 8; ++c) {
    int ch = c * 256 + tid, row = ch >> 4, s = ch & 15;
    pb[c] = Ab + (size_t)row * D_IN + (s ^ ((row >> 1) & 7)) * 8;
    db[c] = 8192u + (uint)ch * 16;
  }

  uint oA[4], oB[4][4];
  {
    int rA = wm * 16 + (lane & 15);
#pragma unroll
    for (int kk = 0; kk < 4; ++kk) {
      int slot = kk * 4 + (lane >> 4);
      oA[kk] = (uint)rA * 256 + (uint)((slot ^ ((rA >> 1) & 7)) * 16);
    }
#pragma unroll
    for (int n = 0; n < 4; ++n) {
      int rB = wn * 64 + n * 16 + (lane & 15);
#pragma unroll
      for (int kk = 0; kk < 4; ++kk) {
        int slot = kk * 4 + (lane >> 4);
        oB[n][kk] = 8192u + (uint)rB * 256 + (uint)((slot ^ ((rB >> 1) & 7)) * 16);
      }
    }
  }

  f32x4 acc[4];
#pragma unroll
  for (int n = 0; n < 4; ++n) acc[n] = (f32x4){0.f, 0.f, 0.f, 0.f};

  HSTG(0); HSTG(1);
  asm volatile("s_waitcnt vmcnt(10)" ::: );
  __builtin_amdgcn_s_barrier();
  __builtin_amdgcn_sched_barrier(0);

#pragma unroll 1
  for (int i3 = 0; i3 < 10; ++i3) {        // tiles 0..29
    HTILE(0, 2, 1, 10);
    HTILE(1, 0, 1, 10);
    HTILE(2, 1, 1, 10);
  }
  HTILE(0, 0, 0, 0);                        // tile 30
  HTILE(1, 0, 0, 0);                        // tile 31

#pragma unroll
  for (int n = 0; n < 4; ++n) {
    int c = wn * 64 + n * 16 + (lane & 15);
    int e = c >> 4;
#pragma unroll
    for (int i = 0; i < 4; ++i) {
      int r = row0 + wm * 16 + (lane >> 4) * 4 + i;
      float v = acc[n][i] * Comb[(size_t)r * 8 + e];
      Xcat[(size_t)r * KCAT + D_IN + c] = f2bf(v);
    }
  }
}

// ---------------- kernel 4: out = Xcat @ Wcat^T + bias ------------------
// R8: 128x128 tile, BK=32, K=4224 (132 tiles), 4 waves (2x2 of 64x64),
// 3-slot LDS ring (48KB -> 3 blocks/CU, 12 waves/CU). Single phase per
// tile: 8 ds_reads + 4 stages -> barrier -> 16 MFMA -> vmcnt(4) -> barrier.
// Inter-block anti-phase overlap (m114) fills read windows; setprio
// arbitrates between co-resident blocks. Ring safety as R3 (stage targets
// slot vacated two barriers ago; vmcnt(4) drains tile t+1 before reads).
#define STG(S) { \
  gload_lds16(pA0, ldsc + (S) * 16384u + dA0); pA0 += 32; \
  gload_lds16(pA1, ldsc + (S) * 16384u + dA1); pA1 += 32; \
  gload_lds16(pB0, ldsc + (S) * 16384u + dB0); pB0 += 32; \
  gload_lds16(pB1, ldsc + (S) * 16384u + dB1); pB1 += 32; }

#define MT(SLOT, SLOTN, DOSTG, VM) { \
  const uint sb = (SLOT) * 16384u; \
  short8 a[4], b[4]; \
  _Pragma("unroll") for (int m = 0; m < 4; ++m) a[m] = *(const short8*)(ldsc + sb + offA[m]); \
  _Pragma("unroll") for (int n = 0; n < 4; ++n) b[n] = *(const short8*)(ldsc + sb + offB[n]); \
  if (DOSTG) STG(SLOTN); \
  __builtin_amdgcn_sched_barrier(0); \
  __builtin_amdgcn_s_barrier(); \
  __builtin_amdgcn_sched_barrier(0); \
  __builtin_amdgcn_s_setprio(1); \
  _Pragma("unroll") for (int m = 0; m < 4; ++m) \
    _Pragma("unroll") for (int n = 0; n < 4; ++n) \
      acc[m][n] = __builtin_amdgcn_mfma_f32_16x16x32_bf16(a[m], b[n], acc[m][n], 0, 0, 0); \
  __builtin_amdgcn_s_setprio(0); \
  __builtin_amdgcn_sched_barrier(0); \
  asm volatile("s_waitcnt vmcnt(" #VM ")" ::: ); \
  __builtin_amdgcn_s_barrier(); \
  __builtin_amdgcn_sched_barrier(0); }

__global__ __launch_bounds__(256, 3) void main_gemm_kernel(
    const unsigned short* __restrict__ Xcat, const unsigned short* __restrict__ Wcat,
    const float* __restrict__ bias, float* __restrict__ Out) {
  __shared__ unsigned short lds[3 * 8192];    // 48 KB: 3 slots x (A 8KB | B 8KB)
  char* ldsc = (char*)lds;
  const int tid = threadIdx.x;
  const int wave = tid >> 6, lane = tid & 63;
  const int wm = wave >> 1, wn = wave & 1;    // 2 x 2 wave grid, 64x64 each
  const int ks = lane >> 4;

  int bid = blockIdx.x;
  int swz = (bid & 7) * 256 + (bid >> 3);     // 2048 blocks, 8 XCDs, bijective
  int mb = swz >> 5, nb = swz & 31;           // 64 x 32 tiles of 128x128
  const int row0 = mb * 128, col0 = nb * 128;

  // staging: A tile 128x32 = 512 chunks of 16B, 2/thread; same for B.
  const unsigned short *pA0, *pA1, *pB0, *pB1;
  uint dA0, dA1, dB0, dB1;
  {
    int ch0 = tid, ch1 = 256 + tid;
    int rr0 = ch0 >> 2, ss0 = (ch0 & 3) ^ ((ch0 >> 3) & 3);
    int rr1 = ch1 >> 2, ss1 = (ch1 & 3) ^ ((ch1 >> 3) & 3);
    pA0 = Xcat + (size_t)(row0 + rr0) * KCAT + ss0 * 8;
    pA1 = Xcat + (size_t)(row0 + rr1) * KCAT + ss1 * 8;
    pB0 = Wcat + (size_t)(col0 + rr0) * KCAT + ss0 * 8;
    pB1 = Wcat + (size_t)(col0 + rr1) * KCAT + ss1 * 8;
    dA0 = (uint)ch0 * 16;          dA1 = (uint)ch1 * 16;
    dB0 = 8192u + (uint)ch0 * 16;  dB1 = 8192u + (uint)ch1 * 16;
  }

  // ds_read offsets (swizzled, R3's zero-conflict pattern):
  // byte = r*64 + (ks ^ ((r>>1)&3))*16
  uint offA[4], offB[4];
#pragma unroll
  for (int mi = 0; mi < 4; ++mi) {
    int r = wm * 64 + mi * 16 + (lane & 15);
    offA[mi] = (uint)r * 64 + (uint)((ks ^ ((r >> 1) & 3)) * 16);
  }
#pragma unroll
  for (int ni = 0; ni < 4; ++ni) {
    int r = wn * 64 + ni * 16 + (lane & 15);
    offB[ni] = 8192u + (uint)r * 64 + (uint)((ks ^ ((r >> 1) & 3)) * 16);
  }

  f32x4 acc[4][4];
#pragma unroll
  for (int mi = 0; mi < 4; ++mi)
#pragma unroll
    for (int ni = 0; ni < 4; ++ni) acc[mi][ni] = (f32x4){0.f, 0.f, 0.f, 0.f};

  // prologue: stage tiles 0,1 into slots 0,1; wait tile 0 (tile 1 in flight)
  STG(0); STG(1);
  asm volatile("s_waitcnt vmcnt(4)" ::: );
  __builtin_amdgcn_s_barrier();
  __builtin_amdgcn_sched_barrier(0);

#pragma unroll 1
  for (int i3 = 0; i3 < 43; ++i3) {           // tiles 0..128, stage 2..130
    MT(0, 2, 1, 4);
    MT(1, 0, 1, 4);
    MT(2, 1, 1, 4);
  }
  MT(0, 2, 1, 4);                              // tile 129, stage 131
  MT(1, 0, 0, 0);                              // tile 130
  MT(2, 0, 0, 0);                              // tile 131

  // epilogue: bias add, f32 store
#pragma unroll
  for (int ni = 0; ni < 4; ++ni) {
    const int c = col0 + wn * 64 + ni * 16 + (lane & 15);
    const float bv = bias[c];
#pragma unroll
    for (int mi = 0; mi < 4; ++mi) {
#pragma unroll
      for (int i = 0; i < 4; ++i) {
        int r = row0 + wm * 64 + mi * 16 + ks * 4 + i;
        Out[(size_t)r * D_OUT + c] = acc[mi][ni][i] + bv;
      }
    }
  }
}

extern "C" void kernel_launch(void* const* d_in, const int* in_sizes, int n_in,
                              void* d_out, int out_size, void* d_ws, size_t ws_size,
                              hipStream_t stream) {
  const float* x        = (const float*)d_in[0];
  const float* W_base   = (const float*)d_in[1];
  const float* b_base   = (const float*)d_in[2];
  const float* W_router = (const float*)d_in[3];
  const float* A_stack  = (const float*)d_in[4];
  const float* B_stack  = (const float*)d_in[5];
  float* out = (float*)d_out;

  char* ws = (char*)d_ws;
  unsigned short* Xcat = (unsigned short*)(ws);                 // 69,206,016 B
  unsigned short* Wcat = (unsigned short*)(ws + 69206016);      // 34,603,008 B
  unsigned short* Ab   = (unsigned short*)(ws + 103809024);     //  1,048,576 B
  float*          Comb = (float*)(ws + 104857600);              //    262,144 B

  hipLaunchKernelGGL(fused_prep_router_kernel, dim3(2560), dim3(256), 0, stream,
                     x, W_router, W_base, A_stack, B_stack, Xcat, Comb, Wcat, Ab);
  hipLaunchKernelGGL(h_gemm_kernel, dim3(256), dim3(256), 0, stream,
                     Xcat, Ab, Comb);
  hipLaunchKernelGGL(main_gemm_kernel, dim3(2048), dim3(256), 0, stream,
                     Xcat, Wcat, b_base, out);
}

// Round 9
// 403.294 us; speedup vs baseline: 1.1627x; 1.1627x over previous
//
#include <hip/hip_runtime.h>

#define D_IN   4096
#define D_OUT  4096
#define N_TOK  8192
#define RANK   16
#define NEXP   8
#define ER     128          // NEXP*RANK — lora inner width
#define KCAT   4224         // D_IN + ER — concatenated K
#define SCALING 2.0f        // 32/16

typedef __attribute__((ext_vector_type(8))) short short8;     // 8 bf16 (4 VGPR)
typedef __attribute__((ext_vector_type(4))) float f32x4;
typedef __attribute__((ext_vector_type(4))) unsigned short us4;
typedef unsigned int uint;

__device__ __forceinline__ unsigned short f2bf(float f) {
  unsigned u = __float_as_uint(f);
  u += 0x7FFFu + ((u >> 16) & 1u);     // RNE
  return (unsigned short)(u >> 16);
}

__device__ __forceinline__ void gload_lds16(const void* g, void* l) {
  __builtin_amdgcn_global_load_lds(
      (const __attribute__((address_space(1))) unsigned int*)g,
      (__attribute__((address_space(3))) unsigned int*)l, 16, 0, 0);
}

// ---------------- kernel 1: weight conversions (standalone) -------------
// Wcat[o][0..4095] = bf16(W_base); Wcat[o][4096+e*16+r] = bf16(B_stack[e][o][r])
// Ab[e*16+r][k] = bf16(A_stack)
__global__ void prep_kernel(const float* __restrict__ W, const float* __restrict__ A,
                            const float* __restrict__ B,
                            unsigned short* __restrict__ Wcat,
                            unsigned short* __restrict__ Ab) {
  const int NW4 = (D_OUT * D_IN) / 4;     // 4194304
  const int NA4 = (ER * D_IN) / 4;        // 131072
  const int NB4 = (D_OUT * ER) / 4;       // 131072
  const int total = NW4 + NA4 + NB4;
  for (int i = blockIdx.x * blockDim.x + threadIdx.x; i < total;
       i += gridDim.x * blockDim.x) {
    if (i < NW4) {
      float4 v = ((const float4*)W)[i];
      us4 o = { f2bf(v.x), f2bf(v.y), f2bf(v.z), f2bf(v.w) };
      int row = i >> 10, kq = i & 1023;
      ((us4*)(Wcat + (size_t)row * KCAT))[kq] = o;
    } else if (i < NW4 + NA4) {
      int j = i - NW4;
      float4 v = ((const float4*)A)[j];
      us4 o = { f2bf(v.x), f2bf(v.y), f2bf(v.z), f2bf(v.w) };
      ((us4*)Ab)[j] = o;
    } else {
      int j = i - NW4 - NA4;              // float4 idx = o*32 + e*4 + rq
      int o = j >> 5; int rem = j & 31; int e = rem >> 2; int rq = rem & 3;
      float4 v = *(const float4*)(B + (size_t)e * D_OUT * RANK + o * RANK + rq * 4);
      us4 ob = { f2bf(v.x), f2bf(v.y), f2bf(v.z), f2bf(v.w) };
      *(us4*)(Wcat + (size_t)o * KCAT + D_IN + e * 16 + rq * 4) = ob;
    }
  }
}

// ---------------- kernel 2: fused router + h_gemm -----------------------
// 256 blocks x 32 tokens. Phase R: x->bf16 (Xcat), f32 logits, top-2 Comb.
// Phase H: h = x_bf @ A_all^T (weighted) -> Xcat[:,4096+], reading the
// block's own Xcat rows (L2-warm) + Ab (prep) + Comb (phase R).
#define HSTG(S) { const uint hbase = (S) * 40960u; \
  _Pragma("unroll") for (int c = 0; c < 2; ++c) { gload_lds16(pa[c], ldsc + hbase + da[c]); pa[c] += 128; } \
  _Pragma("unroll") for (int c = 0; c < 8; ++c) { gload_lds16(pb[c], ldsc + hbase + db[c]); pb[c] += 128; } }

#define HTILE(S, S2, DOSTG, VM) { const uint hb = (S) * 40960u; \
  short8 af[4]; short8 bfr[4][4]; \
  _Pragma("unroll") for (int kk = 0; kk < 4; ++kk) af[kk] = *(const short8*)(ldsc + hb + oA[kk]); \
  _Pragma("unroll") for (int n = 0; n < 4; ++n) \
    _Pragma("unroll") for (int kk = 0; kk < 4; ++kk) bfr[n][kk] = *(const short8*)(ldsc + hb + oB[n][kk]); \
  if (DOSTG) HSTG(S2); \
  __builtin_amdgcn_sched_barrier(0); __builtin_amdgcn_s_barrier(); __builtin_amdgcn_sched_barrier(0); \
  __builtin_amdgcn_s_setprio(1); \
  _Pragma("unroll") for (int kk = 0; kk < 4; ++kk) \
    _Pragma("unroll") for (int n = 0; n < 4; ++n) \
      acc[n] = __builtin_amdgcn_mfma_f32_16x16x32_bf16(af[kk], bfr[n][kk], acc[n], 0, 0, 0); \
  __builtin_amdgcn_s_setprio(0); \
  __builtin_amdgcn_sched_barrier(0); \
  asm volatile("s_waitcnt vmcnt(" #VM ")" ::: ); \
  __builtin_amdgcn_s_barrier(); __builtin_amdgcn_sched_barrier(0); }

__global__ __launch_bounds__(256, 1) void router_h_kernel(
    const float* __restrict__ X, const float* __restrict__ Wr,
    unsigned short* Xcat, const unsigned short* __restrict__ Ab,
    float* __restrict__ Comb) {
  __shared__ unsigned short hlds[61440];     // 3 x 40960 B (phase H only)
  char* ldsc = (char*)hlds;
  const int tid = threadIdx.x, wave = tid >> 6, lane = tid & 63;
  const int row0 = blockIdx.x * 32;

  // ======== phase R: router (8 tokens per wave) ========
  {
    int tok0 = row0 + wave * 8;
    float acc[8][8];
#pragma unroll
    for (int t = 0; t < 8; ++t)
#pragma unroll
      for (int e = 0; e < 8; ++e) acc[t][e] = 0.f;
    const float4* X4 = (const float4*)X;
    const float4* W4 = (const float4*)Wr;
#pragma unroll 1
    for (int it = 0; it < 16; ++it) {
      int kq = it * 64 + lane;
      float4 w[8];
#pragma unroll
      for (int e = 0; e < 8; ++e) w[e] = W4[e * 1024 + kq];
#pragma unroll
      for (int t = 0; t < 8; ++t) {
        float4 xv = X4[(size_t)(tok0 + t) * 1024 + kq];
        us4 xb = { f2bf(xv.x), f2bf(xv.y), f2bf(xv.z), f2bf(xv.w) };
        ((us4*)(Xcat + (size_t)(tok0 + t) * KCAT))[kq] = xb;
#pragma unroll
        for (int e = 0; e < 8; ++e)
          acc[t][e] = fmaf(xv.x, w[e].x, fmaf(xv.y, w[e].y,
                       fmaf(xv.z, w[e].z, fmaf(xv.w, w[e].w, acc[t][e]))));
      }
    }
#pragma unroll
    for (int t = 0; t < 8; ++t)
#pragma unroll
      for (int e = 0; e < 8; ++e) {
        float v = acc[t][e];
        for (int off = 32; off; off >>= 1) v += __shfl_xor(v, off, 64);
        acc[t][e] = v;
      }
#pragma unroll
    for (int t = 0; t < 8; ++t) {
      float m1 = acc[t][0]; int i1 = 0;
#pragma unroll
      for (int e = 1; e < 8; ++e) if (acc[t][e] > m1) { m1 = acc[t][e]; i1 = e; }
      float m2 = -1e30f; int i2 = 0;
#pragma unroll
      for (int e = 0; e < 8; ++e)
        if (e != i1 && acc[t][e] > m2) { m2 = acc[t][e]; i2 = e; }
      float w1 = 1.f / (1.f + expf(m2 - m1));
      if (lane < 8) {
        float v = (lane == i1) ? w1 : (lane == i2) ? (1.f - w1) : 0.f;
        Comb[(size_t)(tok0 + t) * 8 + lane] = v * SCALING;
      }
    }
  }
  // all Xcat/Comb stores drained + block sync before phase H reads them
  asm volatile("s_waitcnt vmcnt(0)" ::: );
  __syncthreads();

  // ======== phase H: h_gemm (R3-verified body) ========
  {
    const int wm = wave >> 1, wn = wave & 1;

    const unsigned short* pa[2]; uint da[2];
#pragma unroll
    for (int c = 0; c < 2; ++c) {
      int ch = c * 256 + tid, row = ch >> 4, s = ch & 15;
      pa[c] = Xcat + (size_t)(row0 + row) * KCAT + (s ^ ((row >> 1) & 7)) * 8;
      da[c] = (uint)ch * 16;
    }
    const unsigned short* pb[8]; uint db[8];
#pragma unroll
    for (int c = 0; c < 8; ++c) {
      int ch = c * 256 + tid, row = ch >> 4, s = ch & 15;
      pb[c] = Ab + (size_t)row * D_IN + (s ^ ((row >> 1) & 7)) * 8;
      db[c] = 8192u + (uint)ch * 16;
    }

    uint oA[4], oB[4][4];
    {
      int rA = wm * 16 + (lane & 15);
#pragma unroll
      for (int kk = 0; kk < 4; ++kk) {
        int slot = kk * 4 + (lane >> 4);
        oA[kk] = (uint)rA * 256 + (uint)((slot ^ ((rA >> 1) & 7)) * 16);
      }
#pragma unroll
      for (int n = 0; n < 4; ++n) {
        int rB = wn * 64 + n * 16 + (lane & 15);
#pragma unroll
        for (int kk = 0; kk < 4; ++kk) {
          int slot = kk * 4 + (lane >> 4);
          oB[n][kk] = 8192u + (uint)rB * 256 + (uint)((slot ^ ((rB >> 1) & 7)) * 16);
        }
      }
    }

    f32x4 acc[4];
#pragma unroll
    for (int n = 0; n < 4; ++n) acc[n] = (f32x4){0.f, 0.f, 0.f, 0.f};

    HSTG(0); HSTG(1);
    asm volatile("s_waitcnt vmcnt(10)" ::: );
    __builtin_amdgcn_s_barrier();
    __builtin_amdgcn_sched_barrier(0);

#pragma unroll 1
    for (int i3 = 0; i3 < 10; ++i3) {        // tiles 0..29
      HTILE(0, 2, 1, 10);
      HTILE(1, 0, 1, 10);
      HTILE(2, 1, 1, 10);
    }
    HTILE(0, 0, 0, 0);                        // tile 30
    HTILE(1, 0, 0, 0);                        // tile 31

#pragma unroll
    for (int n = 0; n < 4; ++n) {
      int c = wn * 64 + n * 16 + (lane & 15);
      int e = c >> 4;
#pragma unroll
      for (int i = 0; i < 4; ++i) {
        int r = row0 + wm * 16 + (lane >> 4) * 4 + i;
        float v = acc[n][i] * Comb[(size_t)r * 8 + e];
        Xcat[(size_t)r * KCAT + D_IN + c] = f2bf(v);
      }
    }
  }
}

// ---------------- kernel 3: out = Xcat @ Wcat^T + bias ------------------
// R3-EXACT (verified anchor: 252us, MfmaUtil 52, 0 conflicts).
// 256x256 tile, BK=32, K=4224 (132 tiles), 4-slot ring, 4-barrier MTILE.
#define STG_A(S) { gload_lds16(pA0, ldsc + (S) * 32768u + dA0); pA0 += 32; \
                   gload_lds16(pA1, ldsc + (S) * 32768u + dA1); pA1 += 32; }
#define STG_B(S) { gload_lds16(pB0, ldsc + (S) * 32768u + dB0); pB0 += 32; \
                   gload_lds16(pB1, ldsc + (S) * 32768u + dB1); pB1 += 32; }

#define MTILE(SLOT, SLOT3, DOSTG, VM) { \
  const uint sb = (SLOT) * 32768u; \
  short8 a0[4], bf[4], a1[4]; \
  _Pragma("unroll") for (int m = 0; m < 4; ++m) a0[m] = *(const short8*)(ldsc + sb + offA[m]); \
  _Pragma("unroll") for (int n = 0; n < 4; ++n) bf[n] = *(const short8*)(ldsc + sb + offB[n]); \
  if (DOSTG) STG_A(SLOT3); \
  __builtin_amdgcn_sched_barrier(0); \
  __builtin_amdgcn_s_barrier(); \
  __builtin_amdgcn_sched_barrier(0); \
  __builtin_amdgcn_s_setprio(1); \
  _Pragma("unroll") for (int m = 0; m < 4; ++m) \
    _Pragma("unroll") for (int n = 0; n < 4; ++n) \
      acc[m][n] = __builtin_amdgcn_mfma_f32_16x16x32_bf16(a0[m], bf[n], acc[m][n], 0, 0, 0); \
  __builtin_amdgcn_s_setprio(0); \
  __builtin_amdgcn_sched_barrier(0); \
  __builtin_amdgcn_s_barrier(); \
  __builtin_amdgcn_sched_barrier(0); \
  _Pragma("unroll") for (int m = 0; m < 4; ++m) a1[m] = *(const short8*)(ldsc + sb + offA[4 + m]); \
  if (DOSTG) STG_B(SLOT3); \
  __builtin_amdgcn_sched_barrier(0); \
  __builtin_amdgcn_s_barrier(); \
  __builtin_amdgcn_sched_barrier(0); \
  __builtin_amdgcn_s_setprio(1); \
  _Pragma("unroll") for (int m = 0; m < 4; ++m) \
    _Pragma("unroll") for (int n = 0; n < 4; ++n) \
      acc[4 + m][n] = __builtin_amdgcn_mfma_f32_16x16x32_bf16(a1[m], bf[n], acc[4 + m][n], 0, 0, 0); \
  __builtin_amdgcn_s_setprio(0); \
  __builtin_amdgcn_sched_barrier(0); \
  asm volatile("s_waitcnt vmcnt(" #VM ")" ::: ); \
  __builtin_amdgcn_s_barrier(); \
  __builtin_amdgcn_sched_barrier(0); }

__global__ __launch_bounds__(512, 2) void main_gemm_kernel(
    const unsigned short* __restrict__ Xcat, const unsigned short* __restrict__ Wcat,
    const float* __restrict__ bias, float* __restrict__ Out) {
  __shared__ unsigned short lds[4 * 16384];   // 128 KB: 4 slots x (A 16KB | B 16KB)
  char* ldsc = (char*)lds;
  const int tid = threadIdx.x;
  const int wave = tid >> 6, lane = tid & 63;
  const int wm = wave >> 2, wn = wave & 3;     // 2 x 4 wave grid
  const int ks = lane >> 4;

  int bid = blockIdx.x;
  int swz = (bid & 7) * 64 + (bid >> 3);       // 512 blocks, 8 XCDs, bijective
  int mb = swz >> 4, nb = swz & 15;            // 32 x 16 tiles
  const int row0 = mb * 256, col0 = nb * 256;

  const unsigned short *pA0, *pA1, *pB0, *pB1;
  uint dA0, dA1, dB0, dB1;
  {
    int ch0 = tid, ch1 = 512 + tid;
    int rr0 = ch0 >> 2, ss0 = (ch0 & 3) ^ ((ch0 >> 3) & 3);
    int rr1 = ch1 >> 2, ss1 = (ch1 & 3) ^ ((ch1 >> 3) & 3);
    pA0 = Xcat + (size_t)(row0 + rr0) * KCAT + ss0 * 8;
    pA1 = Xcat + (size_t)(row0 + rr1) * KCAT + ss1 * 8;
    pB0 = Wcat + (size_t)(col0 + rr0) * KCAT + ss0 * 8;
    pB1 = Wcat + (size_t)(col0 + rr1) * KCAT + ss1 * 8;
    dA0 = (uint)wave * 1024;          dA1 = 8192u + (uint)wave * 1024;
    dB0 = 16384u + (uint)wave * 1024; dB1 = 24576u + (uint)wave * 1024;
  }

  uint offA[8], offB[4];
#pragma unroll
  for (int mi = 0; mi < 8; ++mi) {
    int r = wm * 128 + mi * 16 + (lane & 15);
    offA[mi] = (uint)r * 64 + (uint)((ks ^ ((r >> 1) & 3)) * 16);
  }
#pragma unroll
  for (int ni = 0; ni < 4; ++ni) {
    int r = wn * 64 + ni * 16 + (lane & 15);
    offB[ni] = 16384u + (uint)r * 64 + (uint)((ks ^ ((r >> 1) & 3)) * 16);
  }

  f32x4 acc[8][4];
#pragma unroll
  for (int mi = 0; mi < 8; ++mi)
#pragma unroll
    for (int ni = 0; ni < 4; ++ni) acc[mi][ni] = (f32x4){0.f, 0.f, 0.f, 0.f};

  // prologue: stage tiles 0,1,2 into slots 0,1,2; wait tile 0 (8 in flight)
  STG_A(0); STG_B(0); STG_A(1); STG_B(1); STG_A(2); STG_B(2);
  asm volatile("s_waitcnt vmcnt(8)" ::: );
  __builtin_amdgcn_s_barrier();
  __builtin_amdgcn_sched_barrier(0);

#pragma unroll 1
  for (int i4 = 0; i4 < 32; ++i4) {            // tiles 0..127, stage 3..130
    MTILE(0, 3, 1, 8);
    MTILE(1, 0, 1, 8);
    MTILE(2, 1, 1, 8);
    MTILE(3, 2, 1, 8);
  }
  MTILE(0, 3, 1, 8);                            // tile 128, stage 131
  MTILE(1, 0, 0, 4);                            // tile 129
  MTILE(2, 0, 0, 0);                            // tile 130
  MTILE(3, 0, 0, 0);                            // tile 131

  // epilogue: bias add, f32 store
#pragma unroll
  for (int ni = 0; ni < 4; ++ni) {
    const int c = col0 + wn * 64 + ni * 16 + (lane & 15);
    const float bv = bias[c];
#pragma unroll
    for (int mi = 0; mi < 8; ++mi) {
#pragma unroll
      for (int i = 0; i < 4; ++i) {
        int r = row0 + wm * 128 + mi * 16 + ks * 4 + i;
        Out[(size_t)r * D_OUT + c] = acc[mi][ni][i] + bv;
      }
    }
  }
}

extern "C" void kernel_launch(void* const* d_in, const int* in_sizes, int n_in,
                              void* d_out, int out_size, void* d_ws, size_t ws_size,
                              hipStream_t stream) {
  const float* x        = (const float*)d_in[0];
  const float* W_base   = (const float*)d_in[1];
  const float* b_base   = (const float*)d_in[2];
  const float* W_router = (const float*)d_in[3];
  const float* A_stack  = (const float*)d_in[4];
  const float* B_stack  = (const float*)d_in[5];
  float* out = (float*)d_out;

  char* ws = (char*)d_ws;
  unsigned short* Xcat = (unsigned short*)(ws);                 // 69,206,016 B
  unsigned short* Wcat = (unsigned short*)(ws + 69206016);      // 34,603,008 B
  unsigned short* Ab   = (unsigned short*)(ws + 103809024);     //  1,048,576 B
  float*          Comb = (float*)(ws + 104857600);              //    262,144 B

  hipLaunchKernelGGL(prep_kernel, dim3(2048), dim3(256), 0, stream,
                     W_base, A_stack, B_stack, Wcat, Ab);
  hipLaunchKernelGGL(router_h_kernel, dim3(256), dim3(256), 0, stream,
                     x, W_router, Xcat, Ab, Comb);
  hipLaunchKernelGGL(main_gemm_kernel, dim3(512), dim3(512), 0, stream,
                     Xcat, Wcat, b_base, out);
}

// Round 10
// 362.844 us; speedup vs baseline: 1.2924x; 1.1115x over previous
//
#include <hip/hip_runtime.h>

#define D_IN   4096
#define D_OUT  4096
#define N_TOK  8192
#define RANK   16
#define NEXP   8
#define ER     128          // NEXP*RANK — lora inner width
#define KCAT   4224         // D_IN + ER — concatenated K
#define SCALING 2.0f        // 32/16

typedef __attribute__((ext_vector_type(8))) short short8;     // 8 bf16 (4 VGPR)
typedef __attribute__((ext_vector_type(4))) float f32x4;
typedef __attribute__((ext_vector_type(4))) unsigned short us4;
typedef unsigned int uint;

__device__ __forceinline__ unsigned short f2bf(float f) {
  unsigned u = __float_as_uint(f);
  u += 0x7FFFu + ((u >> 16) & 1u);     // RNE
  return (unsigned short)(u >> 16);
}

__device__ __forceinline__ void gload_lds16(const void* g, void* l) {
  __builtin_amdgcn_global_load_lds(
      (const __attribute__((address_space(1))) unsigned int*)g,
      (__attribute__((address_space(3))) unsigned int*)l, 16, 0, 0);
}

// ---------------- kernel 1: router + x->bf16 + Ab conversion ------------
// 512 blocks x 16 tokens (R5's verified router body). Each thread also
// converts exactly ONE float4 of A_stack into Ab (131072 = 512*256).
__global__ __launch_bounds__(256) void router_kernel(
    const float* __restrict__ X, const float* __restrict__ Wr,
    const float* __restrict__ A,
    unsigned short* __restrict__ Xcat, float* __restrict__ Comb,
    unsigned short* __restrict__ Ab) {
  {
    int j = blockIdx.x * 256 + threadIdx.x;     // Ab: 1 float4 per thread
    float4 v = ((const float4*)A)[j];
    us4 o = { f2bf(v.x), f2bf(v.y), f2bf(v.z), f2bf(v.w) };
    ((us4*)Ab)[j] = o;
  }
  int wave = threadIdx.x >> 6, lane = threadIdx.x & 63;
  int tok0 = blockIdx.x * 16 + wave * 4;
  float acc[4][8];
#pragma unroll
  for (int t = 0; t < 4; ++t)
#pragma unroll
    for (int e = 0; e < 8; ++e) acc[t][e] = 0.f;
  const float4* X4 = (const float4*)X;
  const float4* W4 = (const float4*)Wr;
#pragma unroll 1
  for (int it = 0; it < 16; ++it) {
    int kq = it * 64 + lane;
    float4 w[8];
#pragma unroll
    for (int e = 0; e < 8; ++e) w[e] = W4[e * 1024 + kq];
#pragma unroll
    for (int t = 0; t < 4; ++t) {
      float4 xv = X4[(size_t)(tok0 + t) * 1024 + kq];
      us4 xb = { f2bf(xv.x), f2bf(xv.y), f2bf(xv.z), f2bf(xv.w) };
      ((us4*)(Xcat + (size_t)(tok0 + t) * KCAT))[kq] = xb;
#pragma unroll
      for (int e = 0; e < 8; ++e)
        acc[t][e] = fmaf(xv.x, w[e].x, fmaf(xv.y, w[e].y,
                     fmaf(xv.z, w[e].z, fmaf(xv.w, w[e].w, acc[t][e]))));
    }
  }
#pragma unroll
  for (int t = 0; t < 4; ++t)
#pragma unroll
    for (int e = 0; e < 8; ++e) {
      float v = acc[t][e];
      for (int off = 32; off; off >>= 1) v += __shfl_xor(v, off, 64);
      acc[t][e] = v;
    }
#pragma unroll
  for (int t = 0; t < 4; ++t) {
    float m1 = acc[t][0]; int i1 = 0;
#pragma unroll
    for (int e = 1; e < 8; ++e) if (acc[t][e] > m1) { m1 = acc[t][e]; i1 = e; }
    float m2 = -1e30f; int i2 = 0;
#pragma unroll
    for (int e = 0; e < 8; ++e)
      if (e != i1 && acc[t][e] > m2) { m2 = acc[t][e]; i2 = e; }
    float w1 = 1.f / (1.f + expf(m2 - m1));
    if (lane < 8) {
      float v = (lane == i1) ? w1 : (lane == i2) ? (1.f - w1) : 0.f;
      Comb[(size_t)(tok0 + t) * 8 + lane] = v * SCALING;
    }
  }
}

// ---------------- kernel 2: block-split {h_gemm | prep-W} ---------------
// blocks 0..255: h = x_bf @ A_all^T (weighted) -> Xcat[:,4096+]  (R3 body)
// blocks 256..2303: Wcat[o][k]=bf16(W_base), Wcat[o][4096+e*16+r]=bf16(B_stack)
#define HSTG(S) { const uint hbase = (S) * 40960u; \
  _Pragma("unroll") for (int c = 0; c < 2; ++c) { gload_lds16(pa[c], ldsc + hbase + da[c]); pa[c] += 128; } \
  _Pragma("unroll") for (int c = 0; c < 8; ++c) { gload_lds16(pb[c], ldsc + hbase + db[c]); pb[c] += 128; } }

#define HTILE(S, S2, DOSTG, VM) { const uint hb = (S) * 40960u; \
  short8 af[4]; short8 bfr[4][4]; \
  _Pragma("unroll") for (int kk = 0; kk < 4; ++kk) af[kk] = *(const short8*)(ldsc + hb + oA[kk]); \
  _Pragma("unroll") for (int n = 0; n < 4; ++n) \
    _Pragma("unroll") for (int kk = 0; kk < 4; ++kk) bfr[n][kk] = *(const short8*)(ldsc + hb + oB[n][kk]); \
  if (DOSTG) HSTG(S2); \
  __builtin_amdgcn_sched_barrier(0); __builtin_amdgcn_s_barrier(); __builtin_amdgcn_sched_barrier(0); \
  __builtin_amdgcn_s_setprio(1); \
  _Pragma("unroll") for (int kk = 0; kk < 4; ++kk) \
    _Pragma("unroll") for (int n = 0; n < 4; ++n) \
      acc[n] = __builtin_amdgcn_mfma_f32_16x16x32_bf16(af[kk], bfr[n][kk], acc[n], 0, 0, 0); \
  __builtin_amdgcn_s_setprio(0); \
  __builtin_amdgcn_sched_barrier(0); \
  asm volatile("s_waitcnt vmcnt(" #VM ")" ::: ); \
  __builtin_amdgcn_s_barrier(); __builtin_amdgcn_sched_barrier(0); }

__global__ __launch_bounds__(256, 1) void h_prep_kernel(
    unsigned short* Xcat, const unsigned short* __restrict__ Ab,
    const float* __restrict__ Comb,
    const float* __restrict__ W, const float* __restrict__ B,
    unsigned short* __restrict__ Wcat) {
  __shared__ unsigned short hlds[61440];     // 3 x 40960 B (h path only)
  if (blockIdx.x >= 256) {
    // ---- prep-W part: 2048 blocks grid-stride over W + B ----
    const int NW4 = (D_OUT * D_IN) / 4;     // 4194304
    const int NB4 = (D_OUT * ER) / 4;       // 131072
    const int total = NW4 + NB4;
    const int stride = 2048 * 256;
    for (int i = (blockIdx.x - 256) * blockDim.x + threadIdx.x; i < total;
         i += stride) {
      if (i < NW4) {
        float4 v = ((const float4*)W)[i];
        us4 o = { f2bf(v.x), f2bf(v.y), f2bf(v.z), f2bf(v.w) };
        int row = i >> 10, kq = i & 1023;
        ((us4*)(Wcat + (size_t)row * KCAT))[kq] = o;
      } else {
        int j = i - NW4;                    // float4 idx = o*32 + e*4 + rq
        int o = j >> 5; int rem = j & 31; int e = rem >> 2; int rq = rem & 3;
        float4 v = *(const float4*)(B + (size_t)e * D_OUT * RANK + o * RANK + rq * 4);
        us4 ob = { f2bf(v.x), f2bf(v.y), f2bf(v.z), f2bf(v.w) };
        *(us4*)(Wcat + (size_t)o * KCAT + D_IN + e * 16 + rq * 4) = ob;
      }
    }
    return;
  }
  // ---- h_gemm part (R3-verified body) ----
  char* ldsc = (char*)hlds;
  const int tid = threadIdx.x, wave = tid >> 6, lane = tid & 63;
  const int wm = wave >> 1, wn = wave & 1;
  const int row0 = blockIdx.x * 32;

  const unsigned short* pa[2]; uint da[2];
#pragma unroll
  for (int c = 0; c < 2; ++c) {
    int ch = c * 256 + tid, row = ch >> 4, s = ch & 15;
    pa[c] = Xcat + (size_t)(row0 + row) * KCAT + (s ^ ((row >> 1) & 7)) * 8;
    da[c] = (uint)ch * 16;
  }
  const unsigned short* pb[8]; uint db[8];
#pragma unroll
  for (int c = 0; c < 8; ++c) {
    int ch = c * 256 + tid, row = ch >> 4, s = ch & 15;
    pb[c] = Ab + (size_t)row * D_IN + (s ^ ((row >> 1) & 7)) * 8;
    db[c] = 8192u + (uint)ch * 16;
  }

  uint oA[4], oB[4][4];
  {
    int rA = wm * 16 + (lane & 15);
#pragma unroll
    for (int kk = 0; kk < 4; ++kk) {
      int slot = kk * 4 + (lane >> 4);
      oA[kk] = (uint)rA * 256 + (uint)((slot ^ ((rA >> 1) & 7)) * 16);
    }
#pragma unroll
    for (int n = 0; n < 4; ++n) {
      int rB = wn * 64 + n * 16 + (lane & 15);
#pragma unroll
      for (int kk = 0; kk < 4; ++kk) {
        int slot = kk * 4 + (lane >> 4);
        oB[n][kk] = 8192u + (uint)rB * 256 + (uint)((slot ^ ((rB >> 1) & 7)) * 16);
      }
    }
  }

  f32x4 acc[4];
#pragma unroll
  for (int n = 0; n < 4; ++n) acc[n] = (f32x4){0.f, 0.f, 0.f, 0.f};

  HSTG(0); HSTG(1);
  asm volatile("s_waitcnt vmcnt(10)" ::: );
  __builtin_amdgcn_s_barrier();
  __builtin_amdgcn_sched_barrier(0);

#pragma unroll 1
  for (int i3 = 0; i3 < 10; ++i3) {        // tiles 0..29
    HTILE(0, 2, 1, 10);
    HTILE(1, 0, 1, 10);
    HTILE(2, 1, 1, 10);
  }
  HTILE(0, 0, 0, 0);                        // tile 30
  HTILE(1, 0, 0, 0);                        // tile 31

#pragma unroll
  for (int n = 0; n < 4; ++n) {
    int c = wn * 64 + n * 16 + (lane & 15);
    int e = c >> 4;
#pragma unroll
    for (int i = 0; i < 4; ++i) {
      int r = row0 + wm * 16 + (lane >> 4) * 4 + i;
      float v = acc[n][i] * Comb[(size_t)r * 8 + e];
      Xcat[(size_t)r * KCAT + D_IN + c] = f2bf(v);
    }
  }
}

// ---------------- kernel 3: out = Xcat @ Wcat^T + bias ------------------
// R3-EXACT (verified anchor: ~251us, MfmaUtil 52, 0 conflicts).
// 256x256 tile, BK=32, K=4224 (132 tiles), 4-slot ring, 4-barrier MTILE.
#define STG_A(S) { gload_lds16(pA0, ldsc + (S) * 32768u + dA0); pA0 += 32; \
                   gload_lds16(pA1, ldsc + (S) * 32768u + dA1); pA1 += 32; }
#define STG_B(S) { gload_lds16(pB0, ldsc + (S) * 32768u + dB0); pB0 += 32; \
                   gload_lds16(pB1, ldsc + (S) * 32768u + dB1); pB1 += 32; }

#define MTILE(SLOT, SLOT3, DOSTG, VM) { \
  const uint sb = (SLOT) * 32768u; \
  short8 a0[4], bf[4], a1[4]; \
  _Pragma("unroll") for (int m = 0; m < 4; ++m) a0[m] = *(const short8*)(ldsc + sb + offA[m]); \
  _Pragma("unroll") for (int n = 0; n < 4; ++n) bf[n] = *(const short8*)(ldsc + sb + offB[n]); \
  if (DOSTG) STG_A(SLOT3); \
  __builtin_amdgcn_sched_barrier(0); \
  __builtin_amdgcn_s_barrier(); \
  __builtin_amdgcn_sched_barrier(0); \
  __builtin_amdgcn_s_setprio(1); \
  _Pragma("unroll") for (int m = 0; m < 4; ++m) \
    _Pragma("unroll") for (int n = 0; n < 4; ++n) \
      acc[m][n] = __builtin_amdgcn_mfma_f32_16x16x32_bf16(a0[m], bf[n], acc[m][n], 0, 0, 0); \
  __builtin_amdgcn_s_setprio(0); \
  __builtin_amdgcn_sched_barrier(0); \
  __builtin_amdgcn_s_barrier(); \
  __builtin_amdgcn_sched_barrier(0); \
  _Pragma("unroll") for (int m = 0; m < 4; ++m) a1[m] = *(const short8*)(ldsc + sb + offA[4 + m]); \
  if (DOSTG) STG_B(SLOT3); \
  __builtin_amdgcn_sched_barrier(0); \
  __builtin_amdgcn_s_barrier(); \
  __builtin_amdgcn_sched_barrier(0); \
  __builtin_amdgcn_s_setprio(1); \
  _Pragma("unroll") for (int m = 0; m < 4; ++m) \
    _Pragma("unroll") for (int n = 0; n < 4; ++n) \
      acc[4 + m][n] = __builtin_amdgcn_mfma_f32_16x16x32_bf16(a1[m], bf[n], acc[4 + m][n], 0, 0, 0); \
  __builtin_amdgcn_s_setprio(0); \
  __builtin_amdgcn_sched_barrier(0); \
  asm volatile("s_waitcnt vmcnt(" #VM ")" ::: ); \
  __builtin_amdgcn_s_barrier(); \
  __builtin_amdgcn_sched_barrier(0); }

__global__ __launch_bounds__(512, 2) void main_gemm_kernel(
    const unsigned short* __restrict__ Xcat, const unsigned short* __restrict__ Wcat,
    const float* __restrict__ bias, float* __restrict__ Out) {
  __shared__ unsigned short lds[4 * 16384];   // 128 KB: 4 slots x (A 16KB | B 16KB)
  char* ldsc = (char*)lds;
  const int tid = threadIdx.x;
  const int wave = tid >> 6, lane = tid & 63;
  const int wm = wave >> 2, wn = wave & 3;     // 2 x 4 wave grid
  const int ks = lane >> 4;

  int bid = blockIdx.x;
  int swz = (bid & 7) * 64 + (bid >> 3);       // 512 blocks, 8 XCDs, bijective
  int mb = swz >> 4, nb = swz & 15;            // 32 x 16 tiles
  const int row0 = mb * 256, col0 = nb * 256;

  const unsigned short *pA0, *pA1, *pB0, *pB1;
  uint dA0, dA1, dB0, dB1;
  {
    int ch0 = tid, ch1 = 512 + tid;
    int rr0 = ch0 >> 2, ss0 = (ch0 & 3) ^ ((ch0 >> 3) & 3);
    int rr1 = ch1 >> 2, ss1 = (ch1 & 3) ^ ((ch1 >> 3) & 3);
    pA0 = Xcat + (size_t)(row0 + rr0) * KCAT + ss0 * 8;
    pA1 = Xcat + (size_t)(row0 + rr1) * KCAT + ss1 * 8;
    pB0 = Wcat + (size_t)(col0 + rr0) * KCAT + ss0 * 8;
    pB1 = Wcat + (size_t)(col0 + rr1) * KCAT + ss1 * 8;
    dA0 = (uint)wave * 1024;          dA1 = 8192u + (uint)wave * 1024;
    dB0 = 16384u + (uint)wave * 1024; dB1 = 24576u + (uint)wave * 1024;
  }

  uint offA[8], offB[4];
#pragma unroll
  for (int mi = 0; mi < 8; ++mi) {
    int r = wm * 128 + mi * 16 + (lane & 15);
    offA[mi] = (uint)r * 64 + (uint)((ks ^ ((r >> 1) & 3)) * 16);
  }
#pragma unroll
  for (int ni = 0; ni < 4; ++ni) {
    int r = wn * 64 + ni * 16 + (lane & 15);
    offB[ni] = 16384u + (uint)r * 64 + (uint)((ks ^ ((r >> 1) & 3)) * 16);
  }

  f32x4 acc[8][4];
#pragma unroll
  for (int mi = 0; mi < 8; ++mi)
#pragma unroll
    for (int ni = 0; ni < 4; ++ni) acc[mi][ni] = (f32x4){0.f, 0.f, 0.f, 0.f};

  // prologue: stage tiles 0,1,2 into slots 0,1,2; wait tile 0 (8 in flight)
  STG_A(0); STG_B(0); STG_A(1); STG_B(1); STG_A(2); STG_B(2);
  asm volatile("s_waitcnt vmcnt(8)" ::: );
  __builtin_amdgcn_s_barrier();
  __builtin_amdgcn_sched_barrier(0);

#pragma unroll 1
  for (int i4 = 0; i4 < 32; ++i4) {            // tiles 0..127, stage 3..130
    MTILE(0, 3, 1, 8);
    MTILE(1, 0, 1, 8);
    MTILE(2, 1, 1, 8);
    MTILE(3, 2, 1, 8);
  }
  MTILE(0, 3, 1, 8);                            // tile 128, stage 131
  MTILE(1, 0, 0, 4);                            // tile 129
  MTILE(2, 0, 0, 0);                            // tile 130
  MTILE(3, 0, 0, 0);                            // tile 131

  // epilogue: bias add, f32 store
#pragma unroll
  for (int ni = 0; ni < 4; ++ni) {
    const int c = col0 + wn * 64 + ni * 16 + (lane & 15);
    const float bv = bias[c];
#pragma unroll
    for (int mi = 0; mi < 8; ++mi) {
#pragma unroll
      for (int i = 0; i < 4; ++i) {
        int r = row0 + wm * 128 + mi * 16 + ks * 4 + i;
        Out[(size_t)r * D_OUT + c] = acc[mi][ni][i] + bv;
      }
    }
  }
}

extern "C" void kernel_launch(void* const* d_in, const int* in_sizes, int n_in,
                              void* d_out, int out_size, void* d_ws, size_t ws_size,
                              hipStream_t stream) {
  const float* x        = (const float*)d_in[0];
  const float* W_base   = (const float*)d_in[1];
  const float* b_base   = (const float*)d_in[2];
  const float* W_router = (const float*)d_in[3];
  const float* A_stack  = (const float*)d_in[4];
  const float* B_stack  = (const float*)d_in[5];
  float* out = (float*)d_out;

  char* ws = (char*)d_ws;
  unsigned short* Xcat = (unsigned short*)(ws);                 // 69,206,016 B
  unsigned short* Wcat = (unsigned short*)(ws + 69206016);      // 34,603,008 B
  unsigned short* Ab   = (unsigned short*)(ws + 103809024);     //  1,048,576 B
  float*          Comb = (float*)(ws + 104857600);              //    262,144 B

  hipLaunchKernelGGL(router_kernel, dim3(512), dim3(256), 0, stream,
                     x, W_router, A_stack, Xcat, Comb, Ab);
  hipLaunchKernelGGL(h_prep_kernel, dim3(2304), dim3(256), 0, stream,
                     Xcat, Ab, Comb, W_base, B_stack, Wcat);
  hipLaunchKernelGGL(main_gemm_kernel, dim3(512), dim3(512), 0, stream,
                     Xcat, Wcat, b_base, out);
}

// Round 11
// 332.256 us; speedup vs baseline: 1.4113x; 1.0921x over previous
//
#include <hip/hip_runtime.h>

#define D_IN   4096
#define D_OUT  4096
#define N_TOK  8192
#define RANK   16
#define NEXP   8
#define ER     128          // NEXP*RANK — lora inner width
#define KCAT   4224         // D_IN + ER — concatenated K
#define SCALING 2.0f        // 32/16

typedef __attribute__((ext_vector_type(8))) short short8;     // 8 bf16 (4 VGPR)
typedef __attribute__((ext_vector_type(4))) float f32x4;
typedef __attribute__((ext_vector_type(4))) unsigned short us4;
typedef unsigned int uint;

__device__ __forceinline__ unsigned short f2bf(float f) {
  unsigned u = __float_as_uint(f);
  u += 0x7FFFu + ((u >> 16) & 1u);     // RNE
  return (unsigned short)(u >> 16);
}

__device__ __forceinline__ void gload_lds16(const void* g, void* l) {
  __builtin_amdgcn_global_load_lds(
      (const __attribute__((address_space(1))) unsigned int*)g,
      (__attribute__((address_space(3))) unsigned int*)l, 16, 0, 0);
}

// ---------------- kernel 1: fused prep + router (R5-verified) -----------
// blocks 0..511: x->bf16 (into Xcat) + f32 router + top-2 combine
// blocks 512..2559: weight conversions (Wcat, Ab)
__global__ __launch_bounds__(256) void fused_prep_router_kernel(
    const float* __restrict__ X, const float* __restrict__ Wr,
    const float* __restrict__ W, const float* __restrict__ A,
    const float* __restrict__ B,
    unsigned short* __restrict__ Xcat, float* __restrict__ Comb,
    unsigned short* __restrict__ Wcat, unsigned short* __restrict__ Ab) {
  if (blockIdx.x < 512) {
    // ---- router part ----
    int wave = threadIdx.x >> 6, lane = threadIdx.x & 63;
    int tok0 = blockIdx.x * 16 + wave * 4;
    float acc[4][8];
#pragma unroll
    for (int t = 0; t < 4; ++t)
#pragma unroll
      for (int e = 0; e < 8; ++e) acc[t][e] = 0.f;
    const float4* X4 = (const float4*)X;
    const float4* W4 = (const float4*)Wr;
#pragma unroll 1
    for (int it = 0; it < 16; ++it) {
      int kq = it * 64 + lane;
      float4 w[8];
#pragma unroll
      for (int e = 0; e < 8; ++e) w[e] = W4[e * 1024 + kq];
#pragma unroll
      for (int t = 0; t < 4; ++t) {
        float4 xv = X4[(size_t)(tok0 + t) * 1024 + kq];
        us4 xb = { f2bf(xv.x), f2bf(xv.y), f2bf(xv.z), f2bf(xv.w) };
        ((us4*)(Xcat + (size_t)(tok0 + t) * KCAT))[kq] = xb;
#pragma unroll
        for (int e = 0; e < 8; ++e)
          acc[t][e] = fmaf(xv.x, w[e].x, fmaf(xv.y, w[e].y,
                       fmaf(xv.z, w[e].z, fmaf(xv.w, w[e].w, acc[t][e]))));
      }
    }
#pragma unroll
    for (int t = 0; t < 4; ++t)
#pragma unroll
      for (int e = 0; e < 8; ++e) {
        float v = acc[t][e];
        for (int off = 32; off; off >>= 1) v += __shfl_xor(v, off, 64);
        acc[t][e] = v;
      }
#pragma unroll
    for (int t = 0; t < 4; ++t) {
      float m1 = acc[t][0]; int i1 = 0;
#pragma unroll
      for (int e = 1; e < 8; ++e) if (acc[t][e] > m1) { m1 = acc[t][e]; i1 = e; }
      float m2 = -1e30f; int i2 = 0;
#pragma unroll
      for (int e = 0; e < 8; ++e)
        if (e != i1 && acc[t][e] > m2) { m2 = acc[t][e]; i2 = e; }
      float w1 = 1.f / (1.f + expf(m2 - m1));
      if (lane < 8) {
        float v = (lane == i1) ? w1 : (lane == i2) ? (1.f - w1) : 0.f;
        Comb[(size_t)(tok0 + t) * 8 + lane] = v * SCALING;
      }
    }
  } else {
    // ---- prep part: 2048 blocks grid-stride ----
    const int NW4 = (D_OUT * D_IN) / 4;     // 4194304
    const int NA4 = (ER * D_IN) / 4;        // 131072
    const int NB4 = (D_OUT * ER) / 4;       // 131072
    const int total = NW4 + NA4 + NB4;
    const int stride = 2048 * 256;
    for (int i = (blockIdx.x - 512) * blockDim.x + threadIdx.x; i < total;
         i += stride) {
      if (i < NW4) {
        float4 v = ((const float4*)W)[i];
        us4 o = { f2bf(v.x), f2bf(v.y), f2bf(v.z), f2bf(v.w) };
        int row = i >> 10, kq = i & 1023;
        ((us4*)(Wcat + (size_t)row * KCAT))[kq] = o;
      } else if (i < NW4 + NA4) {
        int j = i - NW4;
        float4 v = ((const float4*)A)[j];
        us4 o = { f2bf(v.x), f2bf(v.y), f2bf(v.z), f2bf(v.w) };
        ((us4*)Ab)[j] = o;
      } else {
        int j = i - NW4 - NA4;              // float4 idx = o*32 + e*4 + rq
        int o = j >> 5; int rem = j & 31; int e = rem >> 2; int rq = rem & 3;
        float4 v = *(const float4*)(B + (size_t)e * D_OUT * RANK + o * RANK + rq * 4);
        us4 ob = { f2bf(v.x), f2bf(v.y), f2bf(v.z), f2bf(v.w) };
        *(us4*)(Wcat + (size_t)o * KCAT + D_IN + e * 16 + rq * 4) = ob;
      }
    }
  }
}

// ---------------- kernel 2: h = x_bf @ A_all^T, weighted -> Xcat[:,4096+] ---
// R3-verified body. 256 blocks x 32 tokens. BK=128, 3-slot LDS ring.
#define HSTG(S) { const uint hbase = (S) * 40960u; \
  _Pragma("unroll") for (int c = 0; c < 2; ++c) { gload_lds16(pa[c], ldsc + hbase + da[c]); pa[c] += 128; } \
  _Pragma("unroll") for (int c = 0; c < 8; ++c) { gload_lds16(pb[c], ldsc + hbase + db[c]); pb[c] += 128; } }

#define HTILE(S, S2, DOSTG, VM) { const uint hb = (S) * 40960u; \
  short8 af[4]; short8 bfr[4][4]; \
  _Pragma("unroll") for (int kk = 0; kk < 4; ++kk) af[kk] = *(const short8*)(ldsc + hb + oA[kk]); \
  _Pragma("unroll") for (int n = 0; n < 4; ++n) \
    _Pragma("unroll") for (int kk = 0; kk < 4; ++kk) bfr[n][kk] = *(const short8*)(ldsc + hb + oB[n][kk]); \
  if (DOSTG) HSTG(S2); \
  __builtin_amdgcn_sched_barrier(0); __builtin_amdgcn_s_barrier(); __builtin_amdgcn_sched_barrier(0); \
  __builtin_amdgcn_s_setprio(1); \
  _Pragma("unroll") for (int kk = 0; kk < 4; ++kk) \
    _Pragma("unroll") for (int n = 0; n < 4; ++n) \
      acc[n] = __builtin_amdgcn_mfma_f32_16x16x32_bf16(af[kk], bfr[n][kk], acc[n], 0, 0, 0); \
  __builtin_amdgcn_s_setprio(0); \
  __builtin_amdgcn_sched_barrier(0); \
  asm volatile("s_waitcnt vmcnt(" #VM ")" ::: ); \
  __builtin_amdgcn_s_barrier(); __builtin_amdgcn_sched_barrier(0); }

__global__ __launch_bounds__(256, 1) void h_gemm_kernel(
    unsigned short* Xcat, const unsigned short* __restrict__ Ab,
    const float* __restrict__ Comb) {
  __shared__ unsigned short hlds[61440];     // 3 x 40960 B
  char* ldsc = (char*)hlds;
  const int tid = threadIdx.x, wave = tid >> 6, lane = tid & 63;
  const int wm = wave >> 1, wn = wave & 1;
  const int row0 = blockIdx.x * 32;

  const unsigned short* pa[2]; uint da[2];
#pragma unroll
  for (int c = 0; c < 2; ++c) {
    int ch = c * 256 + tid, row = ch >> 4, s = ch & 15;
    pa[c] = Xcat + (size_t)(row0 + row) * KCAT + (s ^ ((row >> 1) & 7)) * 8;
    da[c] = (uint)ch * 16;
  }
  const unsigned short* pb[8]; uint db[8];
#pragma unroll
  for (int c = 0; c < 8; ++c) {
    int ch = c * 256 + tid, row = ch >> 4, s = ch & 15;
    pb[c] = Ab + (size_t)row * D_IN + (s ^ ((row >> 1) & 7)) * 8;
    db[c] = 8192u + (uint)ch * 16;
  }

  uint oA[4], oB[4][4];
  {
    int rA = wm * 16 + (lane & 15);
#pragma unroll
    for (int kk = 0; kk < 4; ++kk) {
      int slot = kk * 4 + (lane >> 4);
      oA[kk] = (uint)rA * 256 + (uint)((slot ^ ((rA >> 1) & 7)) * 16);
    }
#pragma unroll
    for (int n = 0; n < 4; ++n) {
      int rB = wn * 64 + n * 16 + (lane & 15);
#pragma unroll
      for (int kk = 0; kk < 4; ++kk) {
        int slot = kk * 4 + (lane >> 4);
        oB[n][kk] = 8192u + (uint)rB * 256 + (uint)((slot ^ ((rB >> 1) & 7)) * 16);
      }
    }
  }

  f32x4 acc[4];
#pragma unroll
  for (int n = 0; n < 4; ++n) acc[n] = (f32x4){0.f, 0.f, 0.f, 0.f};

  HSTG(0); HSTG(1);
  asm volatile("s_waitcnt vmcnt(10)" ::: );
  __builtin_amdgcn_s_barrier();
  __builtin_amdgcn_sched_barrier(0);

#pragma unroll 1
  for (int i3 = 0; i3 < 10; ++i3) {        // tiles 0..29
    HTILE(0, 2, 1, 10);
    HTILE(1, 0, 1, 10);
    HTILE(2, 1, 1, 10);
  }
  HTILE(0, 0, 0, 0);                        // tile 30
  HTILE(1, 0, 0, 0);                        // tile 31

#pragma unroll
  for (int n = 0; n < 4; ++n) {
    int c = wn * 64 + n * 16 + (lane & 15);
    int e = c >> 4;
#pragma unroll
    for (int i = 0; i < 4; ++i) {
      int r = row0 + wm * 16 + (lane >> 4) * 4 + i;
      float v = acc[n][i] * Comb[(size_t)r * 8 + e];
      Xcat[(size_t)r * KCAT + D_IN + c] = f2bf(v);
    }
  }
}

// ---------------- kernel 3: out = Xcat @ Wcat^T + bias ------------------
// R3-EXACT (verified anchor: 249-252us, MfmaUtil 52.4, 0 conflicts).
// 256x256 tile, BK=32, K=4224 (132 tiles), 4-slot ring, 4-barrier MTILE.
#define STG_A(S) { gload_lds16(pA0, ldsc + (S) * 32768u + dA0); pA0 += 32; \
                   gload_lds16(pA1, ldsc + (S) * 32768u + dA1); pA1 += 32; }
#define STG_B(S) { gload_lds16(pB0, ldsc + (S) * 32768u + dB0); pB0 += 32; \
                   gload_lds16(pB1, ldsc + (S) * 32768u + dB1); pB1 += 32; }

#define MTILE(SLOT, SLOT3, DOSTG, VM) { \
  const uint sb = (SLOT) * 32768u; \
  short8 a0[4], bf[4], a1[4]; \
  _Pragma("unroll") for (int m = 0; m < 4; ++m) a0[m] = *(const short8*)(ldsc + sb + offA[m]); \
  _Pragma("unroll") for (int n = 0; n < 4; ++n) bf[n] = *(const short8*)(ldsc + sb + offB[n]); \
  if (DOSTG) STG_A(SLOT3); \
  __builtin_amdgcn_sched_barrier(0); \
  __builtin_amdgcn_s_barrier(); \
  __builtin_amdgcn_sched_barrier(0); \
  __builtin_amdgcn_s_setprio(1); \
  _Pragma("unroll") for (int m = 0; m < 4; ++m) \
    _Pragma("unroll") for (int n = 0; n < 4; ++n) \
      acc[m][n] = __builtin_amdgcn_mfma_f32_16x16x32_bf16(a0[m], bf[n], acc[m][n], 0, 0, 0); \
  __builtin_amdgcn_s_setprio(0); \
  __builtin_amdgcn_sched_barrier(0); \
  __builtin_amdgcn_s_barrier(); \
  __builtin_amdgcn_sched_barrier(0); \
  _Pragma("unroll") for (int m = 0; m < 4; ++m) a1[m] = *(const short8*)(ldsc + sb + offA[4 + m]); \
  if (DOSTG) STG_B(SLOT3); \
  __builtin_amdgcn_sched_barrier(0); \
  __builtin_amdgcn_s_barrier(); \
  __builtin_amdgcn_sched_barrier(0); \
  __builtin_amdgcn_s_setprio(1); \
  _Pragma("unroll") for (int m = 0; m < 4; ++m) \
    _Pragma("unroll") for (int n = 0; n < 4; ++n) \
      acc[4 + m][n] = __builtin_amdgcn_mfma_f32_16x16x32_bf16(a1[m], bf[n], acc[4 + m][n], 0, 0, 0); \
  __builtin_amdgcn_s_setprio(0); \
  __builtin_amdgcn_sched_barrier(0); \
  asm volatile("s_waitcnt vmcnt(" #VM ")" ::: ); \
  __builtin_amdgcn_s_barrier(); \
  __builtin_amdgcn_sched_barrier(0); }

__global__ __launch_bounds__(512, 2) void main_gemm_kernel(
    const unsigned short* __restrict__ Xcat, const unsigned short* __restrict__ Wcat,
    const float* __restrict__ bias, float* __restrict__ Out) {
  __shared__ unsigned short lds[4 * 16384];   // 128 KB: 4 slots x (A 16KB | B 16KB)
  char* ldsc = (char*)lds;
  const int tid = threadIdx.x;
  const int wave = tid >> 6, lane = tid & 63;
  const int wm = wave >> 2, wn = wave & 3;     // 2 x 4 wave grid
  const int ks = lane >> 4;

  int bid = blockIdx.x;
  int swz = (bid & 7) * 64 + (bid >> 3);       // 512 blocks, 8 XCDs, bijective
  int mb = swz >> 4, nb = swz & 15;            // 32 x 16 tiles
  const int row0 = mb * 256, col0 = nb * 256;

  const unsigned short *pA0, *pA1, *pB0, *pB1;
  uint dA0, dA1, dB0, dB1;
  {
    int ch0 = tid, ch1 = 512 + tid;
    int rr0 = ch0 >> 2, ss0 = (ch0 & 3) ^ ((ch0 >> 3) & 3);
    int rr1 = ch1 >> 2, ss1 = (ch1 & 3) ^ ((ch1 >> 3) & 3);
    pA0 = Xcat + (size_t)(row0 + rr0) * KCAT + ss0 * 8;
    pA1 = Xcat + (size_t)(row0 + rr1) * KCAT + ss1 * 8;
    pB0 = Wcat + (size_t)(col0 + rr0) * KCAT + ss0 * 8;
    pB1 = Wcat + (size_t)(col0 + rr1) * KCAT + ss1 * 8;
    dA0 = (uint)wave * 1024;          dA1 = 8192u + (uint)wave * 1024;
    dB0 = 16384u + (uint)wave * 1024; dB1 = 24576u + (uint)wave * 1024;
  }

  uint offA[8], offB[4];
#pragma unroll
  for (int mi = 0; mi < 8; ++mi) {
    int r = wm * 128 + mi * 16 + (lane & 15);
    offA[mi] = (uint)r * 64 + (uint)((ks ^ ((r >> 1) & 3)) * 16);
  }
#pragma unroll
  for (int ni = 0; ni < 4; ++ni) {
    int r = wn * 64 + ni * 16 + (lane & 15);
    offB[ni] = 16384u + (uint)r * 64 + (uint)((ks ^ ((r >> 1) & 3)) * 16);
  }

  f32x4 acc[8][4];
#pragma unroll
  for (int mi = 0; mi < 8; ++mi)
#pragma unroll
    for (int ni = 0; ni < 4; ++ni) acc[mi][ni] = (f32x4){0.f, 0.f, 0.f, 0.f};

  // prologue: stage tiles 0,1,2 into slots 0,1,2; wait tile 0 (8 in flight)
  STG_A(0); STG_B(0); STG_A(1); STG_B(1); STG_A(2); STG_B(2);
  asm volatile("s_waitcnt vmcnt(8)" ::: );
  __builtin_amdgcn_s_barrier();
  __builtin_amdgcn_sched_barrier(0);

#pragma unroll 1
  for (int i4 = 0; i4 < 32; ++i4) {            // tiles 0..127, stage 3..130
    MTILE(0, 3, 1, 8);
    MTILE(1, 0, 1, 8);
    MTILE(2, 1, 1, 8);
    MTILE(3, 2, 1, 8);
  }
  MTILE(0, 3, 1, 8);                            // tile 128, stage 131
  MTILE(1, 0, 0, 4);                            // tile 129
  MTILE(2, 0, 0, 0);                            // tile 130
  MTILE(3, 0, 0, 0);                            // tile 131

  // epilogue: bias add, f32 store
#pragma unroll
  for (int ni = 0; ni < 4; ++ni) {
    const int c = col0 + wn * 64 + ni * 16 + (lane & 15);
    const float bv = bias[c];
#pragma unroll
    for (int mi = 0; mi < 8; ++mi) {
#pragma unroll
      for (int i = 0; i < 4; ++i) {
        int r = row0 + wm * 128 + mi * 16 + ks * 4 + i;
        Out[(size_t)r * D_OUT + c] = acc[mi][ni][i] + bv;
      }
    }
  }
}

extern "C" void kernel_launch(void* const* d_in, const int* in_sizes, int n_in,
                              void* d_out, int out_size, void* d_ws, size_t ws_size,
                              hipStream_t stream) {
  const float* x        = (const float*)d_in[0];
  const float* W_base   = (const float*)d_in[1];
  const float* b_base   = (const float*)d_in[2];
  const float* W_router = (const float*)d_in[3];
  const float* A_stack  = (const float*)d_in[4];
  const float* B_stack  = (const float*)d_in[5];
  float* out = (float*)d_out;

  char* ws = (char*)d_ws;
  unsigned short* Xcat = (unsigned short*)(ws);                 // 69,206,016 B
  unsigned short* Wcat = (unsigned short*)(ws + 69206016);      // 34,603,008 B
  unsigned short* Ab   = (unsigned short*)(ws + 103809024);     //  1,048,576 B
  float*          Comb = (float*)(ws + 104857600);              //    262,144 B

  hipLaunchKernelGGL(fused_prep_router_kernel, dim3(2560), dim3(256), 0, stream,
                     x, W_router, W_base, A_stack, B_stack, Xcat, Comb, Wcat, Ab);
  hipLaunchKernelGGL(h_gemm_kernel, dim3(256), dim3(256), 0, stream,
                     Xcat, Ab, Comb);
  hipLaunchKernelGGL(main_gemm_kernel, dim3(512), dim3(512), 0, stream,
                     Xcat, Wcat, b_base, out);
}